// Round 6
// baseline (63184.247 us; speedup 1.0000x reference)
//
#include <hip/hip_runtime.h>
#include <math.h>

// MPNN on MI355X. R6 = R5 + reinstated zero-init of the segment-sum buffer.
// R5 failed because straddling-run atomicAdds accumulated onto garbage
// (the ping-pong removed the memset). Contained runs: plain store (single
// writer). Straddling runs: ALL writers atomicAdd onto zeroed memory.
// R5's real fix stands: no launch_bounds min-waves (R2-R4 had VGPR=84 <
// 128 live accumulator floats -> 40GB/dispatch scratch-spill traffic).

#define DDIM 128
#define NTOT 128000
#define HBYTES 65536000ULL   // 128000*128*4

__device__ __forceinline__ float gelu_exact(float x) {
    return 0.5f * x * (1.0f + erff(x * 0.70710678118654752440f));
}
__device__ __forceinline__ float sigmoidf_(float x) {
    return 1.0f / (1.0f + expf(-x));
}

__global__ __launch_bounds__(256) void embed_kernel(
    const int* __restrict__ inp, const float* __restrict__ table,
    float* __restrict__ h)
{
    int gid = blockIdx.x * 256 + threadIdx.x;
    if (gid >= NTOT * 32) return;
    int row = gid >> 5;
    int q   = gid & 31;
    int b   = row / 4000;
    int n   = (row % 4000) % 1000;
    int e   = inp[b * 1000 + n];
    ((float4*)h)[gid] = ((const float4*)table)[e * 32 + q];
}

__global__ __launch_bounds__(256) void hist_kernel(
    const int* __restrict__ ni, const int* __restrict__ bi, int E,
    int* __restrict__ deg)
{
    int g = blockIdx.x * 256 + threadIdx.x;
    if (g < E)          atomicAdd(&deg[bi[g]], 1);
    else if (g < 2 * E) atomicAdd(&deg[ni[g - E]], 1);
}

__global__ __launch_bounds__(256) void blockscan_kernel(
    const int* __restrict__ deg, int* __restrict__ offp, int* __restrict__ bsum)
{
    __shared__ int s[256];
    int tid = threadIdx.x;
    int i = blockIdx.x * 256 + tid;
    int v = deg[i];
    s[tid] = v;
    __syncthreads();
    for (int off = 1; off < 256; off <<= 1) {
        int t = (tid >= off) ? s[tid - off] : 0;
        __syncthreads();
        s[tid] += t;
        __syncthreads();
    }
    offp[i] = s[tid] - v;
    if (tid == 255) bsum[blockIdx.x] = s[255];
}

__global__ __launch_bounds__(512) void bscan_kernel(
    const int* __restrict__ bsum, int* __restrict__ bexc, int nb)
{
    __shared__ int s[512];
    int t = threadIdx.x;
    int v = (t < nb) ? bsum[t] : 0;
    s[t] = v;
    __syncthreads();
    for (int off = 1; off < 512; off <<= 1) {
        int u = (t >= off) ? s[t - off] : 0;
        __syncthreads();
        s[t] += u;
        __syncthreads();
    }
    if (t < nb) bexc[t] = s[t] - v;
}

__global__ __launch_bounds__(256) void fill_kernel(
    const int* __restrict__ ni, const int* __restrict__ bi, int E,
    const int* __restrict__ offp, const int* __restrict__ bexc,
    int* __restrict__ cursor, int* __restrict__ elist, int* __restrict__ slotseg)
{
    int g = blockIdx.x * 256 + threadIdx.x;
    if (g >= 2 * E) return;
    int seg = (g < E) ? bi[g] : ni[g - E];
    int pos = atomicAdd(&cursor[seg], 1);
    int slot = offp[seg] + bexc[seg >> 8] + pos;
    elist[slot] = g;
    slotseg[slot] = seg;
}

// Edge MLP over CSR-sorted slots + fused block-level segmented reduction.
// sbuf MUST be zeroed before launch (straddling runs use atomicAdd).
__global__ __launch_bounds__(256) void edge_mlp_csr_kernel(
    const float* __restrict__ h,
    const int* __restrict__ ni, const int* __restrict__ bi, int E,
    const int* __restrict__ elist, const int* __restrict__ slotseg,
    const float* __restrict__ Win,  const float* __restrict__ bin,
    const float* __restrict__ Whid, const float* __restrict__ bhid,
    const float* __restrict__ Wout, const float* __restrict__ bout,
    float* __restrict__ sbuf)
{
    __shared__ float w[4096];          // 16KB weight chunk
    __shared__ float scat[16 * 68];    // transpose batch (stride 68)
    __shared__ int   segLDS[256];
    __shared__ int   segedge[2];
    const int tid  = threadIdx.x;
    const int lane = tid & 63;
    const int wv   = tid >> 6;
    const int s0   = blockIdx.x * 256;
    const int slot = s0 + tid;

    const int seg = slotseg[slot];               // -1 for padded slots
    const int g   = (seg >= 0) ? elist[slot] : 0;
    int first = 0, second = 0;
    if (seg >= 0) {
        if (g < E) { first = ni[g];     second = bi[g];     }
        else       { first = bi[g - E]; second = ni[g - E]; }
    }
    segLDS[tid] = seg;
    if (tid == 0) segedge[0] = slotseg[s0 - 1];
    if (tid == 1) segedge[1] = slotseg[s0 + 256];

    const float* rowp0 = h + (size_t)first  * DDIM;
    const float* rowp1 = h + (size_t)second * DDIM;

    // ---- stage 1: x[256] @ W_in[256x64] + b_in, gelu; 4 chunks ----
    float hcur[64];
    #pragma unroll
    for (int j = 0; j < 64; ++j) hcur[j] = bin[j];

    for (int c = 0; c < 4; ++c) {
        const float4* xb = (const float4*)((c < 2) ? rowp0 : rowp1) + (c & 1) * 16;
        float4 xv[8];
        #pragma unroll
        for (int q = 0; q < 8; ++q) xv[q] = xb[q];
        __syncthreads();
        for (int i4 = tid; i4 < 1024; i4 += 256)
            ((float4*)w)[i4] = ((const float4*)(Win + c * 4096))[i4];
        __syncthreads();
        #pragma unroll
        for (int q = 0; q < 8; ++q) {
            #pragma unroll
            for (int kk = 0; kk < 4; ++kk) {
                const float xk = (&xv[q].x)[kk];
                const float* wr = &w[(q * 4 + kk) * 64];
                #pragma unroll
                for (int j = 0; j < 64; ++j) hcur[j] = fmaf(xk, wr[j], hcur[j]);
            }
        }
        #pragma unroll
        for (int q = 0; q < 8; ++q) xv[q] = xb[8 + q];
        #pragma unroll
        for (int q = 0; q < 8; ++q) {
            #pragma unroll
            for (int kk = 0; kk < 4; ++kk) {
                const float xk = (&xv[q].x)[kk];
                const float* wr = &w[(32 + q * 4 + kk) * 64];
                #pragma unroll
                for (int j = 0; j < 64; ++j) hcur[j] = fmaf(xk, wr[j], hcur[j]);
            }
        }
    }
    #pragma unroll
    for (int j = 0; j < 64; ++j) hcur[j] = gelu_exact(hcur[j]);

    // ---- 3 hidden layers 64x64 ----
    for (int L = 0; L < 3; ++L) {
        __syncthreads();
        for (int i4 = tid; i4 < 1024; i4 += 256)
            ((float4*)w)[i4] = ((const float4*)(Whid + L * 4096))[i4];
        __syncthreads();
        float acc[64];
        #pragma unroll
        for (int j = 0; j < 64; ++j) acc[j] = bhid[L * 64 + j];
        #pragma unroll
        for (int k = 0; k < 64; ++k) {
            const float xk = hcur[k];
            const float* wr = &w[k * 64];
            #pragma unroll
            for (int j = 0; j < 64; ++j) acc[j] = fmaf(xk, wr[j], acc[j]);
        }
        #pragma unroll
        for (int j = 0; j < 64; ++j) hcur[j] = gelu_exact(acc[j]);
    }

    // ---- output layer (two 64-col halves) + fused segmented reduction ----
    for (int half = 0; half < 2; ++half) {
        __syncthreads();
        for (int i4 = tid; i4 < 1024; i4 += 256) {
            int k = i4 >> 4, jq = i4 & 15;
            ((float4*)w)[i4] = *(const float4*)(Wout + k * 128 + half * 64 + jq * 4);
        }
        __syncthreads();
        float acc[64];
        #pragma unroll
        for (int j = 0; j < 64; ++j) acc[j] = bout[half * 64 + j];
        #pragma unroll
        for (int k = 0; k < 64; ++k) {
            const float xk = hcur[k];
            const float* wr = &w[k * 64];
            #pragma unroll
            for (int j = 0; j < 64; ++j) acc[j] = fmaf(xk, wr[j], acc[j]);
        }

        int   runSeg = -2;
        float runacc = 0.0f;
        bool  leftC  = true;
        for (int b = 0; b < 16; ++b) {
            __syncthreads();
            if ((tid >> 4) == b) {
                float4* dp = (float4*)&scat[(tid & 15) * 68];
                #pragma unroll
                for (int q = 0; q < 16; ++q)
                    dp[q] = make_float4(acc[q*4], acc[q*4+1], acc[q*4+2], acc[q*4+3]);
            }
            __syncthreads();
            if (wv == 0) {
                for (int r = 0; r < 16; ++r) {
                    const int rowi = b * 16 + r;
                    const int sg = segLDS[rowi];
                    const float v = scat[r * 68 + lane];
                    if (sg != runSeg) {
                        if (runSeg >= 0) {
                            // run ended inside block; leftC => contained
                            float* p = sbuf + (size_t)runSeg * DDIM + half * 64 + lane;
                            if (leftC) *p = runacc;
                            else       atomicAdd(p, runacc);
                        }
                        runSeg = sg;
                        runacc = v;
                        leftC  = (rowi == 0) ? (segedge[0] != sg) : true;
                    } else {
                        runacc += v;
                    }
                }
            }
        }
        if (wv == 0 && runSeg >= 0) {
            const bool rightC = (segedge[1] != runSeg);
            float* p = sbuf + (size_t)runSeg * DDIM + half * 64 + lane;
            if (leftC && rightC) *p = runacc;     // contained
            else                 atomicAdd(p, runacc);  // straddles a boundary
        }
        __syncthreads();
    }
}

// GRU (keras reset_after). block=256, thread-per-node, grid=500.
// Reads h (bufA) + msum (bufB, zero-inited then edge-filled);
// writes h' into bufB rows after all reads (ping-pong).
#define GRU_PASS(ACC, ROWP, W, CB, SCALE)                                      \
    for (int s = 0; s < 2; ++s) {                                              \
        __syncthreads();                                                       \
        for (int i4 = tid; i4 < 1024; i4 += 256) {                             \
            int kk = i4 >> 4, jq = i4 & 15;                                    \
            ((float4*)w)[i4] =                                                 \
                *((const float4*)((W) + (s * 64 + kk) * 384 + (CB)) + jq);     \
        }                                                                      \
        __syncthreads();                                                       \
        const float4* rp4 = (const float4*)(ROWP) + s * 16;                    \
        _Pragma("unroll 2")                                                    \
        for (int k4 = 0; k4 < 16; ++k4) {                                      \
            float4 xv4 = rp4[k4];                                              \
            _Pragma("unroll")                                                  \
            for (int kk = 0; kk < 4; ++kk) {                                   \
                float xk = (&xv4.x)[kk] * (SCALE);                             \
                const float* wr = &w[(k4 * 4 + kk) * 64];                      \
                _Pragma("unroll")                                              \
                for (int j = 0; j < 64; ++j) ACC[j] = fmaf(xk, wr[j], ACC[j]); \
            }                                                                  \
        }                                                                      \
    }

__global__ __launch_bounds__(256) void gru_kernel(
    const float* __restrict__ h, float* __restrict__ msum,
    const int* __restrict__ deg,
    const float* __restrict__ Wx, const float* __restrict__ Wh,
    const float* __restrict__ bi, const float* __restrict__ br)
{
    __shared__ float w[4096];          // 16KB weight stage
    const int tid  = threadIdx.x;
    const int node = blockIdx.x * 256 + tid;
    const int dg   = deg[node];
    const float cinv = (dg > 0) ? (1.0f / (float)dg) : 0.0f;
    const float* mrow = msum + (size_t)node * DDIM;
    const float* hrow = h    + (size_t)node * DDIM;
    float*       orow = msum + (size_t)node * DDIM;   // same row, written last

    float o0[64];
    for (int half = 0; half < 2; ++half) {
        const int cb = half * 64;
        // r_pre = xr + hr
        float rv[64];
        #pragma unroll
        for (int j = 0; j < 64; ++j) rv[j] = bi[128 + cb + j] + br[128 + cb + j];
        GRU_PASS(rv, mrow, Wx, 128 + cb, cinv)
        GRU_PASS(rv, hrow, Wh, 128 + cb, 1.0f)
        // hh
        float hh[64];
        #pragma unroll
        for (int j = 0; j < 64; ++j) hh[j] = br[256 + cb + j];
        GRU_PASS(hh, hrow, Wh, 256 + cb, 1.0f)
        // cand = tanh(xh + sigmoid(r)*hh)
        #pragma unroll
        for (int j = 0; j < 64; ++j)
            rv[j] = sigmoidf_(rv[j]) * hh[j] + bi[256 + cb + j];
        GRU_PASS(rv, mrow, Wx, 256 + cb, cinv)
        #pragma unroll
        for (int j = 0; j < 64; ++j) rv[j] = tanhf(rv[j]);
        // z_pre
        #pragma unroll
        for (int j = 0; j < 64; ++j) hh[j] = bi[cb + j] + br[cb + j];
        GRU_PASS(hh, mrow, Wx, cb, cinv)
        GRU_PASS(hh, hrow, Wh, cb, 1.0f)
        // blend
        if (half == 0) {
            #pragma unroll
            for (int q = 0; q < 16; ++q) {
                float4 hc = ((const float4*)hrow)[q];
                #pragma unroll
                for (int kk = 0; kk < 4; ++kk) {
                    int j = q * 4 + kk;
                    float z = sigmoidf_(hh[j]);
                    o0[j] = z * (&hc.x)[kk] + (1.0f - z) * rv[j];
                }
            }
        } else {
            float4 o1[16];
            #pragma unroll
            for (int q = 0; q < 16; ++q) {
                float4 hc = ((const float4*)hrow)[16 + q];
                #pragma unroll
                for (int kk = 0; kk < 4; ++kk) {
                    int j = q * 4 + kk;
                    float z = sigmoidf_(hh[j]);
                    (&o1[q].x)[kk] = z * (&hc.x)[kk] + (1.0f - z) * rv[j];
                }
            }
            #pragma unroll
            for (int q = 0; q < 16; ++q)
                ((float4*)orow)[q] = make_float4(o0[q*4], o0[q*4+1],
                                                 o0[q*4+2], o0[q*4+3]);
            #pragma unroll
            for (int q = 0; q < 16; ++q) ((float4*)orow)[16 + q] = o1[q];
        }
    }
}

__global__ __launch_bounds__(64) void readout_kernel(
    const float* __restrict__ h,
    const float* __restrict__ Win,  const float* __restrict__ bin,
    const float* __restrict__ Whid, const float* __restrict__ bhid,
    const float* __restrict__ Wout, const float* __restrict__ bout,
    float* __restrict__ out)
{
    __shared__ float w[4096];
    const int tid = threadIdx.x;
    const int row = blockIdx.x * 64 + tid;        // 0..31999
    const int b = row / 1000, n = row % 1000;
    const float4* xrow = (const float4*)(h + ((size_t)b * 4000 + n) * DDIM);

    float hcur[64];
    #pragma unroll
    for (int j = 0; j < 64; ++j) hcur[j] = bin[j];

    for (int c = 0; c < 2; ++c) {
        __syncthreads();
        for (int i4 = tid; i4 < 1024; i4 += 64)
            ((float4*)w)[i4] = ((const float4*)(Win + c * 4096))[i4];
        __syncthreads();
        #pragma unroll
        for (int k4 = 0; k4 < 16; ++k4) {
            float4 xv = xrow[c * 16 + k4];
            #pragma unroll
            for (int kk = 0; kk < 4; ++kk) {
                float xk = (&xv.x)[kk];
                const float* wr = &w[(k4 * 4 + kk) * 64];
                #pragma unroll
                for (int j = 0; j < 64; ++j) hcur[j] = fmaf(xk, wr[j], hcur[j]);
            }
        }
    }
    #pragma unroll
    for (int j = 0; j < 64; ++j) hcur[j] = gelu_exact(hcur[j]);

    for (int L = 0; L < 3; ++L) {
        __syncthreads();
        for (int i4 = tid; i4 < 1024; i4 += 64)
            ((float4*)w)[i4] = ((const float4*)(Whid + L * 4096))[i4];
        __syncthreads();
        float acc[64];
        #pragma unroll
        for (int j = 0; j < 64; ++j) acc[j] = bhid[L * 64 + j];
        #pragma unroll
        for (int k = 0; k < 64; ++k) {
            float xk = hcur[k];
            const float* wr = &w[k * 64];
            #pragma unroll
            for (int j = 0; j < 64; ++j) acc[j] = fmaf(xk, wr[j], acc[j]);
        }
        #pragma unroll
        for (int j = 0; j < 64; ++j) hcur[j] = gelu_exact(acc[j]);
    }

    __syncthreads();
    for (int i = tid; i < 640; i += 64) w[i] = Wout[i];
    __syncthreads();

    float acc[10];
    #pragma unroll
    for (int p = 0; p < 10; ++p) acc[p] = bout[p];
    #pragma unroll
    for (int k = 0; k < 64; ++k) {
        float xk = hcur[k];
        #pragma unroll
        for (int p = 0; p < 10; ++p) acc[p] = fmaf(xk, w[k * 10 + p], acc[p]);
    }
    #pragma unroll
    for (int p = 0; p < 10; ++p) out[(size_t)row * 10 + p] = acc[p];
}

extern "C" void kernel_launch(void* const* d_in, const int* in_sizes, int n_in,
                              void* d_out, int out_size, void* d_ws, size_t ws_size,
                              hipStream_t stream) {
    const int*   node_inputs = (const int*)d_in[0];
    const int*   ni_int = (const int*)d_in[1];
    const int*   bi_int = (const int*)d_in[2];
    const int*   ni_tmp = (const int*)d_in[3];
    const int*   bi_tmp = (const int*)d_in[4];
    const float* embed  = (const float*)d_in[5];
    const float* mWin   = (const float*)d_in[6];
    const float* mbin   = (const float*)d_in[7];
    const float* mWhid  = (const float*)d_in[8];
    const float* mbhid  = (const float*)d_in[9];
    const float* mWout  = (const float*)d_in[10];
    const float* mbout  = (const float*)d_in[11];
    const float* roWin  = (const float*)d_in[12];
    const float* robin  = (const float*)d_in[13];
    const float* roWhid = (const float*)d_in[14];
    const float* robhid = (const float*)d_in[15];
    const float* roWout = (const float*)d_in[16];
    const float* robout = (const float*)d_in[17];
    const float* giWx = (const float*)d_in[18];
    const float* giWh = (const float*)d_in[19];
    const float* gibi = (const float*)d_in[20];
    const float* gibr = (const float*)d_in[21];
    const float* gtWx = (const float*)d_in[22];
    const float* gtWh = (const float*)d_in[23];
    const float* gtbi = (const float*)d_in[24];
    const float* gtbr = (const float*)d_in[25];
    float* out = (float*)d_out;

    const int E_INT = 200000, E_TMP = 96000;
    const int NSLOT_I = 400128;   // 1563*256 (padded), 400000 valid
    const int NSLOT_T = 192000;   // 750*256 exact

    char* ws = (char*)d_ws;
    float* buf0 = (float*)(ws);
    float* buf1 = (float*)(ws + HBYTES);
    char*  ib   = ws + 2 * HBYTES;
    int* deg_i   = (int*)(ib);
    int* deg_t   = (int*)(ib + 512000);
    int* offp_i  = (int*)(ib + 1024000);
    int* offp_t  = (int*)(ib + 1536000);
    int* bexc_i  = (int*)(ib + 2048000);
    int* bexc_t  = (int*)(ib + 2052096);
    int* bsum    = (int*)(ib + 2056192);
    int* cursor  = (int*)(ib + 2060288);
    int* el_i    = (int*)(ib + 2572288);
    int* el_t    = (int*)(ib + 4172800);
    int* ssi_raw = (int*)(ib + 4940800);
    int* sst_raw = (int*)(ib + 6541320);
    int* ssi = ssi_raw + 1;
    int* sst = sst_raw + 1;

    embed_kernel<<<16000, 256, 0, stream>>>(node_inputs, embed, buf0);

    hipMemsetAsync(deg_i, 0, NTOT * sizeof(int), stream);
    hipMemsetAsync(deg_t, 0, NTOT * sizeof(int), stream);
    hist_kernel<<<(2 * E_INT + 255) / 256, 256, 0, stream>>>(ni_int, bi_int, E_INT, deg_i);
    hist_kernel<<<(2 * E_TMP + 255) / 256, 256, 0, stream>>>(ni_tmp, bi_tmp, E_TMP, deg_t);

    hipMemsetAsync(ssi_raw, 0xFF, (size_t)(NSLOT_I + 2) * sizeof(int), stream);
    hipMemsetAsync(sst_raw, 0xFF, (size_t)(NSLOT_T + 2) * sizeof(int), stream);

    blockscan_kernel<<<500, 256, 0, stream>>>(deg_i, offp_i, bsum);
    bscan_kernel<<<1, 512, 0, stream>>>(bsum, bexc_i, 500);
    hipMemsetAsync(cursor, 0, NTOT * sizeof(int), stream);
    fill_kernel<<<(2 * E_INT + 255) / 256, 256, 0, stream>>>(
        ni_int, bi_int, E_INT, offp_i, bexc_i, cursor, el_i, ssi);

    blockscan_kernel<<<500, 256, 0, stream>>>(deg_t, offp_t, bsum);
    bscan_kernel<<<1, 512, 0, stream>>>(bsum, bexc_t, 500);
    hipMemsetAsync(cursor, 0, NTOT * sizeof(int), stream);
    fill_kernel<<<(2 * E_TMP + 255) / 256, 256, 0, stream>>>(
        ni_tmp, bi_tmp, E_TMP, offp_t, bexc_t, cursor, el_t, sst);

    // ping-pong: h in hc; ho zeroed, edge writes sums, GRU writes h' into ho
    float* hc = buf0;
    float* ho = buf1;
    for (int t = 0; t < 2; ++t) {
        hipMemsetAsync(ho, 0, HBYTES, stream);
        edge_mlp_csr_kernel<<<NSLOT_I / 256, 256, 0, stream>>>(
            hc, ni_int, bi_int, E_INT, el_i, ssi,
            mWin, mbin, mWhid, mbhid, mWout, mbout, ho);
        gru_kernel<<<NTOT / 256, 256, 0, stream>>>(
            hc, ho, deg_i, giWx, giWh, gibi, gibr);
        { float* tmp = hc; hc = ho; ho = tmp; }

        hipMemsetAsync(ho, 0, HBYTES, stream);
        edge_mlp_csr_kernel<<<NSLOT_T / 256, 256, 0, stream>>>(
            hc, ni_tmp, bi_tmp, E_TMP, el_t, sst,
            mWin, mbin, mWhid, mbhid, mWout, mbout, ho);
        gru_kernel<<<NTOT / 256, 256, 0, stream>>>(
            hc, ho, deg_t, gtWx, gtWh, gtbi, gtbr);
        { float* tmp = hc; hc = ho; ho = tmp; }
    }

    readout_kernel<<<500, 64, 0, stream>>>(
        hc, roWin, robin, roWhid, robhid, roWout, robout, out);
}

// Round 7
// 7084.103 us; speedup vs baseline: 8.9192x; 8.9192x over previous
//
#include <hip/hip_runtime.h>
#include <math.h>

// MPNN on MI355X. R7: kill register-spill by construction — at most ONE
// 64-float register array live per kernel; activations ride in per-thread
// LDS slices (stride 65 -> 2-way bank alias, free). R6 evidence: VGPR=256
// (maxed) with FETCH~=WRITE~=17GB -> hcur[64]+acc[64]+LDS-temps overflowed
// even 256 VGPRs; every prior round was scratch-bound.
// GRU: 16-col chunked (4x16 accs), 3-buffer rotation (needs ws>=205MB,
// else falls back to R6 monolithic GRU).

#define DDIM 128
#define NTOT 128000
#define HBYTES 65536000ULL   // 128000*128*4
#define EBLK 128

__device__ __forceinline__ float gelu_exact(float x) {
    return 0.5f * x * (1.0f + erff(x * 0.70710678118654752440f));
}
__device__ __forceinline__ float sigmoidf_(float x) {
    return 1.0f / (1.0f + expf(-x));
}

__global__ __launch_bounds__(256) void embed_kernel(
    const int* __restrict__ inp, const float* __restrict__ table,
    float* __restrict__ h)
{
    int gid = blockIdx.x * 256 + threadIdx.x;
    if (gid >= NTOT * 32) return;
    int row = gid >> 5;
    int q   = gid & 31;
    int b   = row / 4000;
    int n   = (row % 4000) % 1000;
    int e   = inp[b * 1000 + n];
    ((float4*)h)[gid] = ((const float4*)table)[e * 32 + q];
}

__global__ __launch_bounds__(256) void hist_kernel(
    const int* __restrict__ ni, const int* __restrict__ bi, int E,
    int* __restrict__ deg)
{
    int g = blockIdx.x * 256 + threadIdx.x;
    if (g < E)          atomicAdd(&deg[bi[g]], 1);
    else if (g < 2 * E) atomicAdd(&deg[ni[g - E]], 1);
}

__global__ __launch_bounds__(256) void blockscan_kernel(
    const int* __restrict__ deg, int* __restrict__ offp, int* __restrict__ bsum)
{
    __shared__ int s[256];
    int tid = threadIdx.x;
    int i = blockIdx.x * 256 + tid;
    int v = deg[i];
    s[tid] = v;
    __syncthreads();
    for (int off = 1; off < 256; off <<= 1) {
        int t = (tid >= off) ? s[tid - off] : 0;
        __syncthreads();
        s[tid] += t;
        __syncthreads();
    }
    offp[i] = s[tid] - v;
    if (tid == 255) bsum[blockIdx.x] = s[255];
}

__global__ __launch_bounds__(512) void bscan_kernel(
    const int* __restrict__ bsum, int* __restrict__ bexc, int nb)
{
    __shared__ int s[512];
    int t = threadIdx.x;
    int v = (t < nb) ? bsum[t] : 0;
    s[t] = v;
    __syncthreads();
    for (int off = 1; off < 512; off <<= 1) {
        int u = (t >= off) ? s[t - off] : 0;
        __syncthreads();
        s[t] += u;
        __syncthreads();
    }
    if (t < nb) bexc[t] = s[t] - v;
}

__global__ __launch_bounds__(256) void fill_kernel(
    const int* __restrict__ ni, const int* __restrict__ bi, int E,
    const int* __restrict__ offp, const int* __restrict__ bexc,
    int* __restrict__ cursor, int* __restrict__ elist, int* __restrict__ slotseg)
{
    int g = blockIdx.x * 256 + threadIdx.x;
    if (g >= 2 * E) return;
    int seg = (g < E) ? bi[g] : ni[g - E];
    int pos = atomicAdd(&cursor[seg], 1);
    int slot = offp[seg] + bexc[seg >> 8] + pos;
    elist[slot] = g;
    slotseg[slot] = seg;
}

// Edge MLP over CSR-sorted slots + fused block segmented reduction.
// Block = 128 threads. Activations in per-thread LDS slice xs[tid*65+...].
// Only one 64-float register accumulator live at any time.
__global__ __launch_bounds__(EBLK) void edge_mlp_csr_kernel(
    const float* __restrict__ h,
    const int* __restrict__ ni, const int* __restrict__ bi, int E,
    const int* __restrict__ elist, const int* __restrict__ slotseg,
    const float* __restrict__ Win,  const float* __restrict__ bin,
    const float* __restrict__ Whid, const float* __restrict__ bhid,
    const float* __restrict__ Wout, const float* __restrict__ bout,
    float* __restrict__ sbuf)
{
    __shared__ float xs[EBLK * 65];    // 33.3 KB activations (2-way alias, free)
    __shared__ float w[2048];          // 8 KB weight chunk
    __shared__ float scat[16 * 68];    // 4.35 KB transpose batch
    __shared__ int   segLDS[EBLK];
    __shared__ int   segedge[2];
    const int tid  = threadIdx.x;
    const int lane = tid & 63;
    const int s0   = blockIdx.x * EBLK;
    const int slot = s0 + tid;

    const int seg = slotseg[slot];
    const int g   = (seg >= 0) ? elist[slot] : 0;
    int first = 0, second = 0;
    if (seg >= 0) {
        if (g < E) { first = ni[g];     second = bi[g];     }
        else       { first = bi[g - E]; second = ni[g - E]; }
    }
    segLDS[tid] = seg;
    if (tid == 0) segedge[0] = slotseg[s0 - 1];
    if (tid == 1) segedge[1] = slotseg[s0 + EBLK];

    const float* rowp0 = h + (size_t)first  * DDIM;
    const float* rowp1 = h + (size_t)second * DDIM;

    // ---- stage 1: x[256] @ W_in[256x64]; 8 chunks of 32 k-rows ----
    {
        float acc[64];
        #pragma unroll
        for (int j = 0; j < 64; ++j) acc[j] = bin[j];
        for (int c = 0; c < 8; ++c) {
            const float4* xb = (const float4*)((c < 4) ? rowp0 : rowp1) + (c & 3) * 8;
            float4 xv[8];
            #pragma unroll
            for (int q = 0; q < 8; ++q) xv[q] = xb[q];
            __syncthreads();
            for (int i4 = tid; i4 < 512; i4 += EBLK)
                ((float4*)w)[i4] = ((const float4*)(Win + c * 2048))[i4];
            __syncthreads();
            #pragma unroll
            for (int q = 0; q < 8; ++q) {
                #pragma unroll
                for (int kk = 0; kk < 4; ++kk) {
                    const float xk = (&xv[q].x)[kk];
                    const float* wr = &w[(q * 4 + kk) * 64];
                    #pragma unroll
                    for (int j = 0; j < 64; ++j) acc[j] = fmaf(xk, wr[j], acc[j]);
                }
            }
        }
        #pragma unroll
        for (int j = 0; j < 64; ++j) xs[tid * 65 + j] = gelu_exact(acc[j]);
    }

    // ---- 3 hidden layers 64x64; weight chunks of 32 rows ----
    for (int L = 0; L < 3; ++L) {
        float acc[64];
        #pragma unroll
        for (int j = 0; j < 64; ++j) acc[j] = bhid[L * 64 + j];
        for (int s = 0; s < 2; ++s) {
            __syncthreads();
            for (int i4 = tid; i4 < 512; i4 += EBLK)
                ((float4*)w)[i4] = ((const float4*)(Whid + L * 4096 + s * 2048))[i4];
            __syncthreads();
            #pragma unroll 4
            for (int k = 0; k < 32; ++k) {
                const float xk = xs[tid * 65 + s * 32 + k];
                const float* wr = &w[k * 64];
                #pragma unroll
                for (int j = 0; j < 64; ++j) acc[j] = fmaf(xk, wr[j], acc[j]);
            }
        }
        #pragma unroll
        for (int j = 0; j < 64; ++j) xs[tid * 65 + j] = gelu_exact(acc[j]);
    }

    // ---- output 64x128 (two halves) + fused segmented reduction ----
    for (int half = 0; half < 2; ++half) {
        float acc[64];
        #pragma unroll
        for (int j = 0; j < 64; ++j) acc[j] = bout[half * 64 + j];
        for (int s = 0; s < 2; ++s) {
            __syncthreads();
            for (int i4 = tid; i4 < 512; i4 += EBLK) {
                int k = i4 >> 4, jq = i4 & 15;
                ((float4*)w)[i4] =
                    *(const float4*)(Wout + (s * 32 + k) * 128 + half * 64 + jq * 4);
            }
            __syncthreads();
            #pragma unroll 4
            for (int k = 0; k < 32; ++k) {
                const float xk = xs[tid * 65 + s * 32 + k];
                const float* wr = &w[k * 64];
                #pragma unroll
                for (int j = 0; j < 64; ++j) acc[j] = fmaf(xk, wr[j], acc[j]);
            }
        }

        int   runSeg = -2;
        float runacc = 0.0f;
        bool  leftC  = true;
        for (int b = 0; b < 8; ++b) {
            __syncthreads();
            if ((tid >> 4) == b) {
                float4* dp = (float4*)&scat[(tid & 15) * 68];
                #pragma unroll
                for (int q = 0; q < 16; ++q)
                    dp[q] = make_float4(acc[q*4], acc[q*4+1], acc[q*4+2], acc[q*4+3]);
            }
            __syncthreads();
            if (tid < 64) {
                for (int r = 0; r < 16; ++r) {
                    const int rowi = b * 16 + r;
                    const int sg = segLDS[rowi];
                    const float v = scat[r * 68 + lane];
                    if (sg != runSeg) {
                        if (runSeg >= 0) {
                            float* p = sbuf + (size_t)runSeg * DDIM + half * 64 + lane;
                            if (leftC) *p = runacc;
                            else       atomicAdd(p, runacc);
                        }
                        runSeg = sg;
                        runacc = v;
                        leftC  = (rowi == 0) ? (segedge[0] != sg) : true;
                    } else {
                        runacc += v;
                    }
                }
            }
        }
        if (tid < 64 && runSeg >= 0) {
            const bool rightC = (segedge[1] != runSeg);
            float* p = sbuf + (size_t)runSeg * DDIM + half * 64 + lane;
            if (leftC && rightC) *p = runacc;
            else                 atomicAdd(p, runacc);
        }
        __syncthreads();
    }
}

// Chunked GRU (fast path): thread-per-node, h' in 8 chunks of 16 cols.
// 4x16 register accs only; per-chunk 48KB LDS weight slices.
// Writes h' to a THIRD buffer (hout != h != msum).
__global__ __launch_bounds__(256) void gru_chunk_kernel(
    const float* __restrict__ h, const float* __restrict__ msum,
    const int* __restrict__ deg,
    const float* __restrict__ Wx, const float* __restrict__ Wh,
    const float* __restrict__ bi, const float* __restrict__ br,
    float* __restrict__ hout)
{
    __shared__ float w[12288];     // 48 KB: 6 slices [128][16]
    const int tid  = threadIdx.x;
    const int node = blockIdx.x * 256 + tid;
    const int dg   = deg[node];
    const float cinv = (dg > 0) ? (1.0f / (float)dg) : 0.0f;
    const float4* m4p = (const float4*)(msum + (size_t)node * DDIM);
    const float4* h4p = (const float4*)(h    + (size_t)node * DDIM);
    float* orow = hout + (size_t)node * DDIM;

    for (int ch = 0; ch < 8; ++ch) {
        const int j0 = ch * 16;
        __syncthreads();
        // slices: 0=Wx_z 1=Wx_r 2=Wx_h 3=Wh_z 4=Wh_r 5=Wh_h, each [128][16]
        for (int i = tid; i < 3072; i += 256) {
            int s  = i >> 9;
            int k  = (i >> 2) & 127;
            int jq = i & 3;
            const float* W = (s < 3) ? Wx : Wh;
            int gate = (s < 3) ? s : (s - 3);
            ((float4*)w)[i] = *(const float4*)(W + k * 384 + gate * 128 + j0 + jq * 4);
        }
        __syncthreads();

        float az[16], ar[16], ax[16], ah[16];
        #pragma unroll
        for (int j = 0; j < 16; ++j) {
            az[j] = bi[j0 + j]       + br[j0 + j];
            ar[j] = bi[128 + j0 + j] + br[128 + j0 + j];
            ax[j] = bi[256 + j0 + j];
            ah[j] = br[256 + j0 + j];
        }
        for (int k4 = 0; k4 < 32; ++k4) {
            float4 mv4 = m4p[k4];
            float4 hv4 = h4p[k4];
            #pragma unroll
            for (int kk = 0; kk < 4; ++kk) {
                const int k = k4 * 4 + kk;
                const float mk = (&mv4.x)[kk] * cinv;
                const float hk = (&hv4.x)[kk];
                const float* wzx = &w[k * 16];
                const float* wrx = &w[2048 + k * 16];
                const float* whx = &w[4096 + k * 16];
                const float* wzh = &w[6144 + k * 16];
                const float* wrh = &w[8192 + k * 16];
                const float* whh = &w[10240 + k * 16];
                #pragma unroll
                for (int j = 0; j < 16; ++j) {
                    az[j] = fmaf(mk, wzx[j], az[j]);
                    az[j] = fmaf(hk, wzh[j], az[j]);
                    ar[j] = fmaf(mk, wrx[j], ar[j]);
                    ar[j] = fmaf(hk, wrh[j], ar[j]);
                    ax[j] = fmaf(mk, whx[j], ax[j]);
                    ah[j] = fmaf(hk, whh[j], ah[j]);
                }
            }
        }
        float4 hj4[4];
        #pragma unroll
        for (int q = 0; q < 4; ++q) hj4[q] = h4p[ch * 4 + q];
        float4 o[4];
        #pragma unroll
        for (int j = 0; j < 16; ++j) {
            float z    = sigmoidf_(az[j]);
            float r    = sigmoidf_(ar[j]);
            float cand = tanhf(ax[j] + r * ah[j]);
            float hv   = (&hj4[j >> 2].x)[j & 3];
            (&o[j >> 2].x)[j & 3] = z * hv + (1.0f - z) * cand;
        }
        #pragma unroll
        for (int q = 0; q < 4; ++q) ((float4*)orow)[ch * 4 + q] = o[q];
    }
}

// Fallback GRU (2-buffer): R6 monolithic, in-place on msum. Spilly but correct.
#define GRU_PASS(ACC, ROWP, W, CB, SCALE)                                      \
    for (int s = 0; s < 2; ++s) {                                              \
        __syncthreads();                                                       \
        for (int i4 = tid; i4 < 1024; i4 += 256) {                             \
            int kk = i4 >> 4, jq = i4 & 15;                                    \
            ((float4*)w)[i4] =                                                 \
                *((const float4*)((W) + (s * 64 + kk) * 384 + (CB)) + jq);     \
        }                                                                      \
        __syncthreads();                                                       \
        const float4* rp4 = (const float4*)(ROWP) + s * 16;                    \
        _Pragma("unroll 2")                                                    \
        for (int k4 = 0; k4 < 16; ++k4) {                                      \
            float4 xv4 = rp4[k4];                                              \
            _Pragma("unroll")                                                  \
            for (int kk = 0; kk < 4; ++kk) {                                   \
                float xk = (&xv4.x)[kk] * (SCALE);                             \
                const float* wr = &w[(k4 * 4 + kk) * 64];                      \
                _Pragma("unroll")                                              \
                for (int j = 0; j < 64; ++j) ACC[j] = fmaf(xk, wr[j], ACC[j]); \
            }                                                                  \
        }                                                                      \
    }

__global__ __launch_bounds__(256) void gru_fallback_kernel(
    const float* __restrict__ h, float* __restrict__ msum,
    const int* __restrict__ deg,
    const float* __restrict__ Wx, const float* __restrict__ Wh,
    const float* __restrict__ bi, const float* __restrict__ br)
{
    __shared__ float w[4096];
    const int tid  = threadIdx.x;
    const int node = blockIdx.x * 256 + tid;
    const int dg   = deg[node];
    const float cinv = (dg > 0) ? (1.0f / (float)dg) : 0.0f;
    const float* mrow = msum + (size_t)node * DDIM;
    const float* hrow = h    + (size_t)node * DDIM;
    float*       orow = msum + (size_t)node * DDIM;

    float o0[64];
    for (int half = 0; half < 2; ++half) {
        const int cb = half * 64;
        float rv[64];
        #pragma unroll
        for (int j = 0; j < 64; ++j) rv[j] = bi[128 + cb + j] + br[128 + cb + j];
        GRU_PASS(rv, mrow, Wx, 128 + cb, cinv)
        GRU_PASS(rv, hrow, Wh, 128 + cb, 1.0f)
        float hh[64];
        #pragma unroll
        for (int j = 0; j < 64; ++j) hh[j] = br[256 + cb + j];
        GRU_PASS(hh, hrow, Wh, 256 + cb, 1.0f)
        #pragma unroll
        for (int j = 0; j < 64; ++j)
            rv[j] = sigmoidf_(rv[j]) * hh[j] + bi[256 + cb + j];
        GRU_PASS(rv, mrow, Wx, 256 + cb, cinv)
        #pragma unroll
        for (int j = 0; j < 64; ++j) rv[j] = tanhf(rv[j]);
        #pragma unroll
        for (int j = 0; j < 64; ++j) hh[j] = bi[cb + j] + br[cb + j];
        GRU_PASS(hh, mrow, Wx, cb, cinv)
        GRU_PASS(hh, hrow, Wh, cb, 1.0f)
        if (half == 0) {
            #pragma unroll
            for (int q = 0; q < 16; ++q) {
                float4 hc = ((const float4*)hrow)[q];
                #pragma unroll
                for (int kk = 0; kk < 4; ++kk) {
                    int j = q * 4 + kk;
                    float z = sigmoidf_(hh[j]);
                    o0[j] = z * (&hc.x)[kk] + (1.0f - z) * rv[j];
                }
            }
        } else {
            float4 o1[16];
            #pragma unroll
            for (int q = 0; q < 16; ++q) {
                float4 hc = ((const float4*)hrow)[16 + q];
                #pragma unroll
                for (int kk = 0; kk < 4; ++kk) {
                    int j = q * 4 + kk;
                    float z = sigmoidf_(hh[j]);
                    (&o1[q].x)[kk] = z * (&hc.x)[kk] + (1.0f - z) * rv[j];
                }
            }
            #pragma unroll
            for (int q = 0; q < 16; ++q)
                ((float4*)orow)[q] = make_float4(o0[q*4], o0[q*4+1],
                                                 o0[q*4+2], o0[q*4+3]);
            #pragma unroll
            for (int q = 0; q < 16; ++q) ((float4*)orow)[16 + q] = o1[q];
        }
    }
}

// Readout: block=64, activations in LDS slice, one 64-float acc array.
__global__ __launch_bounds__(64) void readout_kernel(
    const float* __restrict__ h,
    const float* __restrict__ Win,  const float* __restrict__ bin,
    const float* __restrict__ Whid, const float* __restrict__ bhid,
    const float* __restrict__ Wout, const float* __restrict__ bout,
    float* __restrict__ out)
{
    __shared__ float xs[64 * 65];   // 16.6 KB
    __shared__ float w[4096];       // 16 KB
    const int tid = threadIdx.x;
    const int row = blockIdx.x * 64 + tid;        // 0..31999
    const int b = row / 1000, n = row % 1000;
    const float4* xrow = (const float4*)(h + ((size_t)b * 4000 + n) * DDIM);

    {
        float acc[64];
        #pragma unroll
        for (int j = 0; j < 64; ++j) acc[j] = bin[j];
        for (int c = 0; c < 2; ++c) {
            __syncthreads();
            for (int i4 = tid; i4 < 1024; i4 += 64)
                ((float4*)w)[i4] = ((const float4*)(Win + c * 4096))[i4];
            __syncthreads();
            #pragma unroll 4
            for (int k4 = 0; k4 < 16; ++k4) {
                float4 xv = xrow[c * 16 + k4];
                #pragma unroll
                for (int kk = 0; kk < 4; ++kk) {
                    float xk = (&xv.x)[kk];
                    const float* wr = &w[(k4 * 4 + kk) * 64];
                    #pragma unroll
                    for (int j = 0; j < 64; ++j) acc[j] = fmaf(xk, wr[j], acc[j]);
                }
            }
        }
        #pragma unroll
        for (int j = 0; j < 64; ++j) xs[tid * 65 + j] = gelu_exact(acc[j]);
    }

    for (int L = 0; L < 3; ++L) {
        float acc[64];
        #pragma unroll
        for (int j = 0; j < 64; ++j) acc[j] = bhid[L * 64 + j];
        __syncthreads();
        for (int i4 = tid; i4 < 1024; i4 += 64)
            ((float4*)w)[i4] = ((const float4*)(Whid + L * 4096))[i4];
        __syncthreads();
        #pragma unroll 4
        for (int k = 0; k < 64; ++k) {
            const float xk = xs[tid * 65 + k];
            const float* wr = &w[k * 64];
            #pragma unroll
            for (int j = 0; j < 64; ++j) acc[j] = fmaf(xk, wr[j], acc[j]);
        }
        #pragma unroll
        for (int j = 0; j < 64; ++j) xs[tid * 65 + j] = gelu_exact(acc[j]);
    }

    __syncthreads();
    for (int i = tid; i < 640; i += 64) w[i] = Wout[i];
    __syncthreads();

    float acc[10];
    #pragma unroll
    for (int p = 0; p < 10; ++p) acc[p] = bout[p];
    #pragma unroll
    for (int k = 0; k < 64; ++k) {
        const float xk = xs[tid * 65 + k];
        #pragma unroll
        for (int p = 0; p < 10; ++p) acc[p] = fmaf(xk, w[k * 10 + p], acc[p]);
    }
    #pragma unroll
    for (int p = 0; p < 10; ++p) out[(size_t)row * 10 + p] = acc[p];
}

extern "C" void kernel_launch(void* const* d_in, const int* in_sizes, int n_in,
                              void* d_out, int out_size, void* d_ws, size_t ws_size,
                              hipStream_t stream) {
    const int*   node_inputs = (const int*)d_in[0];
    const int*   ni_int = (const int*)d_in[1];
    const int*   bi_int = (const int*)d_in[2];
    const int*   ni_tmp = (const int*)d_in[3];
    const int*   bi_tmp = (const int*)d_in[4];
    const float* embed  = (const float*)d_in[5];
    const float* mWin   = (const float*)d_in[6];
    const float* mbin   = (const float*)d_in[7];
    const float* mWhid  = (const float*)d_in[8];
    const float* mbhid  = (const float*)d_in[9];
    const float* mWout  = (const float*)d_in[10];
    const float* mbout  = (const float*)d_in[11];
    const float* roWin  = (const float*)d_in[12];
    const float* robin  = (const float*)d_in[13];
    const float* roWhid = (const float*)d_in[14];
    const float* robhid = (const float*)d_in[15];
    const float* roWout = (const float*)d_in[16];
    const float* robout = (const float*)d_in[17];
    const float* giWx = (const float*)d_in[18];
    const float* giWh = (const float*)d_in[19];
    const float* gibi = (const float*)d_in[20];
    const float* gibr = (const float*)d_in[21];
    const float* gtWx = (const float*)d_in[22];
    const float* gtWh = (const float*)d_in[23];
    const float* gtbi = (const float*)d_in[24];
    const float* gtbr = (const float*)d_in[25];
    float* out = (float*)d_out;

    const int E_INT = 200000, E_TMP = 96000;
    const int NSLOT_I = 400000;   // 3125*128 exact
    const int NSLOT_T = 192000;   // 1500*128 exact

    const size_t NEED_FAST = 3 * HBYTES + 8ULL * 1024 * 1024;
    const bool fast = (ws_size >= NEED_FAST);

    char* ws = (char*)d_ws;
    float* B0 = (float*)(ws);
    float* B1 = (float*)(ws + HBYTES);
    float* B2 = fast ? (float*)(ws + 2 * HBYTES) : (float*)0;
    char*  ib = ws + (fast ? 3 : 2) * HBYTES;

    int* deg_i   = (int*)(ib);
    int* deg_t   = (int*)(ib + 512000);
    int* offp_i  = (int*)(ib + 1024000);
    int* offp_t  = (int*)(ib + 1536000);
    int* bexc_i  = (int*)(ib + 2048000);
    int* bexc_t  = (int*)(ib + 2052096);
    int* bsum    = (int*)(ib + 2056192);
    int* cursor  = (int*)(ib + 2060288);
    int* el_i    = (int*)(ib + 2572288);            // 400000*4
    int* el_t    = (int*)(ib + 4172288);            // 192000*4
    int* ssi_raw = (int*)(ib + 4940288);            // (1+400000+1)*4
    int* sst_raw = (int*)(ib + 6540296);            // (1+192000+1)*4
    int* ssi = ssi_raw + 1;
    int* sst = sst_raw + 1;

    embed_kernel<<<16000, 256, 0, stream>>>(node_inputs, embed, B0);

    hipMemsetAsync(deg_i, 0, NTOT * sizeof(int), stream);
    hipMemsetAsync(deg_t, 0, NTOT * sizeof(int), stream);
    hist_kernel<<<(2 * E_INT + 255) / 256, 256, 0, stream>>>(ni_int, bi_int, E_INT, deg_i);
    hist_kernel<<<(2 * E_TMP + 255) / 256, 256, 0, stream>>>(ni_tmp, bi_tmp, E_TMP, deg_t);

    hipMemsetAsync(ssi_raw, 0xFF, (size_t)(NSLOT_I + 2) * sizeof(int), stream);
    hipMemsetAsync(sst_raw, 0xFF, (size_t)(NSLOT_T + 2) * sizeof(int), stream);

    blockscan_kernel<<<500, 256, 0, stream>>>(deg_i, offp_i, bsum);
    bscan_kernel<<<1, 512, 0, stream>>>(bsum, bexc_i, 500);
    hipMemsetAsync(cursor, 0, NTOT * sizeof(int), stream);
    fill_kernel<<<(2 * E_INT + 255) / 256, 256, 0, stream>>>(
        ni_int, bi_int, E_INT, offp_i, bexc_i, cursor, el_i, ssi);

    blockscan_kernel<<<500, 256, 0, stream>>>(deg_t, offp_t, bsum);
    bscan_kernel<<<1, 512, 0, stream>>>(bsum, bexc_t, 500);
    hipMemsetAsync(cursor, 0, NTOT * sizeof(int), stream);
    fill_kernel<<<(2 * E_TMP + 255) / 256, 256, 0, stream>>>(
        ni_tmp, bi_tmp, E_TMP, offp_t, bexc_t, cursor, el_t, sst);

    if (fast) {
        // 3-buffer rotation: (h, sum, hnew)
        float* hb = B0; float* sb = B1; float* nb = B2;
        for (int p = 0; p < 4; ++p) {
            const bool isInt = (p % 2 == 0);
            hipMemsetAsync(sb, 0, HBYTES, stream);
            if (isInt) {
                edge_mlp_csr_kernel<<<NSLOT_I / EBLK, EBLK, 0, stream>>>(
                    hb, ni_int, bi_int, E_INT, el_i, ssi,
                    mWin, mbin, mWhid, mbhid, mWout, mbout, sb);
                gru_chunk_kernel<<<NTOT / 256, 256, 0, stream>>>(
                    hb, sb, deg_i, giWx, giWh, gibi, gibr, nb);
            } else {
                edge_mlp_csr_kernel<<<NSLOT_T / EBLK, EBLK, 0, stream>>>(
                    hb, ni_tmp, bi_tmp, E_TMP, el_t, sst,
                    mWin, mbin, mWhid, mbhid, mWout, mbout, sb);
                gru_chunk_kernel<<<NTOT / 256, 256, 0, stream>>>(
                    hb, sb, deg_t, gtWx, gtWh, gtbi, gtbr, nb);
            }
            float* t0 = hb; hb = nb; nb = sb; sb = t0;
        }
        readout_kernel<<<500, 64, 0, stream>>>(
            hb, roWin, robin, roWhid, robhid, roWout, robout, out);
    } else {
        // 2-buffer fallback: GRU in-place on sum buffer
        float* hc = B0; float* ho = B1;
        for (int p = 0; p < 4; ++p) {
            const bool isInt = (p % 2 == 0);
            hipMemsetAsync(ho, 0, HBYTES, stream);
            if (isInt) {
                edge_mlp_csr_kernel<<<NSLOT_I / EBLK, EBLK, 0, stream>>>(
                    hc, ni_int, bi_int, E_INT, el_i, ssi,
                    mWin, mbin, mWhid, mbhid, mWout, mbout, ho);
                gru_fallback_kernel<<<NTOT / 256, 256, 0, stream>>>(
                    hc, ho, deg_i, giWx, giWh, gibi, gibr);
            } else {
                edge_mlp_csr_kernel<<<NSLOT_T / EBLK, EBLK, 0, stream>>>(
                    hc, ni_tmp, bi_tmp, E_TMP, el_t, sst,
                    mWin, mbin, mWhid, mbhid, mWout, mbout, ho);
                gru_fallback_kernel<<<NTOT / 256, 256, 0, stream>>>(
                    hc, ho, deg_t, gtWx, gtWh, gtbi, gtbr);
            }
            float* tmp = hc; hc = ho; ho = tmp;
        }
        readout_kernel<<<500, 64, 0, stream>>>(
            hc, roWin, robin, roWhid, robhid, roWout, robout, out);
    }
}

// Round 8
// 5770.284 us; speedup vs baseline: 10.9499x; 1.2277x over previous
//
#include <hip/hip_runtime.h>
#include <math.h>

// MPNN on MI355X. R8: (1) weights read directly from global with wave-uniform
// addresses -> compiler scalarizes to s_load/SGPR, v_fma takes the SGPR
// operand; no LDS weight staging (edge was ds_read-issue-bound: 9.2k b128
// broadcasts vs 36.9k FMA per row). (2) stage-1 factorized per NODE:
// [ha||hb]@Win = Wtop@ha + Wbot@hb -> node_pre kernel (-45% edge FLOP,
// gathers halve). p rides in the 3-buffer rotation (no extra workspace).

#define DDIM 128
#define NTOT 128000
#define HBYTES 65536000ULL   // 128000*128*4
#define EBLK 128

__device__ __forceinline__ float gelu_exact(float x) {
    return 0.5f * x * (1.0f + erff(x * 0.70710678118654752440f));
}
__device__ __forceinline__ float sigmoidf_(float x) {
    return 1.0f / (1.0f + expf(-x));
}

__global__ __launch_bounds__(256) void embed_kernel(
    const int* __restrict__ inp, const float* __restrict__ table,
    float* __restrict__ h)
{
    int gid = blockIdx.x * 256 + threadIdx.x;
    if (gid >= NTOT * 32) return;
    int row = gid >> 5;
    int q   = gid & 31;
    int b   = row / 4000;
    int n   = (row % 4000) % 1000;
    int e   = inp[b * 1000 + n];
    ((float4*)h)[gid] = ((const float4*)table)[e * 32 + q];
}

__global__ __launch_bounds__(256) void hist_kernel(
    const int* __restrict__ ni, const int* __restrict__ bi, int E,
    int* __restrict__ deg)
{
    int g = blockIdx.x * 256 + threadIdx.x;
    if (g < E)          atomicAdd(&deg[bi[g]], 1);
    else if (g < 2 * E) atomicAdd(&deg[ni[g - E]], 1);
}

__global__ __launch_bounds__(256) void blockscan_kernel(
    const int* __restrict__ deg, int* __restrict__ offp, int* __restrict__ bsum)
{
    __shared__ int s[256];
    int tid = threadIdx.x;
    int i = blockIdx.x * 256 + tid;
    int v = deg[i];
    s[tid] = v;
    __syncthreads();
    for (int off = 1; off < 256; off <<= 1) {
        int t = (tid >= off) ? s[tid - off] : 0;
        __syncthreads();
        s[tid] += t;
        __syncthreads();
    }
    offp[i] = s[tid] - v;
    if (tid == 255) bsum[blockIdx.x] = s[255];
}

__global__ __launch_bounds__(512) void bscan_kernel(
    const int* __restrict__ bsum, int* __restrict__ bexc, int nb)
{
    __shared__ int s[512];
    int t = threadIdx.x;
    int v = (t < nb) ? bsum[t] : 0;
    s[t] = v;
    __syncthreads();
    for (int off = 1; off < 512; off <<= 1) {
        int u = (t >= off) ? s[t - off] : 0;
        __syncthreads();
        s[t] += u;
        __syncthreads();
    }
    if (t < nb) bexc[t] = s[t] - v;
}

__global__ __launch_bounds__(256) void fill_kernel(
    const int* __restrict__ ni, const int* __restrict__ bi, int E,
    const int* __restrict__ offp, const int* __restrict__ bexc,
    int* __restrict__ cursor, int* __restrict__ elist, int* __restrict__ slotseg)
{
    int g = blockIdx.x * 256 + threadIdx.x;
    if (g >= 2 * E) return;
    int seg = (g < E) ? bi[g] : ni[g - E];
    int pos = atomicAdd(&cursor[seg], 1);
    int slot = offp[seg] + bexc[seg >> 8] + pos;
    elist[slot] = g;
    slotseg[slot] = seg;
}

// Per-node stage-1 factorization: p[v][0:64) = Wtop@h[v] + bin,
// p[v][64:128) = Wbot@h[v]. Weights uniform -> scalar loads.
__global__ __launch_bounds__(256) void node_pre_kernel(
    const float* __restrict__ h, const float* __restrict__ Win,
    const float* __restrict__ bin, float* __restrict__ p)
{
    const int node = blockIdx.x * 256 + threadIdx.x;
    const float4* h4 = (const float4*)(h + (size_t)node * DDIM);
    float* prow = p + (size_t)node * DDIM;

    for (int c = 0; c < 4; ++c) {        // c<2: top cols c*32; c>=2: bot cols (c-2)*32
        const int top   = (c < 2) ? 1 : 0;
        const int j0    = (c & 1) * 32;
        const int kbase = top ? 0 : 128;
        float acc[32];
        #pragma unroll
        for (int j = 0; j < 32; ++j) acc[j] = top ? bin[j0 + j] : 0.0f;
        for (int k4 = 0; k4 < 32; ++k4) {
            float4 hv = h4[k4];
            #pragma unroll
            for (int kk = 0; kk < 4; ++kk) {
                const float hk = (&hv.x)[kk];
                const float* wr = Win + (size_t)(kbase + k4 * 4 + kk) * 64 + j0;
                #pragma unroll
                for (int j = 0; j < 32; ++j) acc[j] = fmaf(hk, wr[j], acc[j]);
            }
        }
        float* dst = prow + (top ? 0 : 64) + j0;
        #pragma unroll
        for (int q = 0; q < 8; ++q)
            ((float4*)dst)[q] = make_float4(acc[q*4], acc[q*4+1],
                                            acc[q*4+2], acc[q*4+3]);
    }
}

// Edge MLP from precomputed p, CSR-sorted slots + fused segmented reduction.
// x = gelu(ptop[first] + pbot[second]); weights from global (uniform/scalar).
__global__ __launch_bounds__(EBLK) void edge_mlp_kernel3(
    const int* __restrict__ ni, const int* __restrict__ bi, int E,
    const int* __restrict__ elist, const int* __restrict__ slotseg,
    const float* __restrict__ p,
    const float* __restrict__ Whid, const float* __restrict__ bhid,
    const float* __restrict__ Wout, const float* __restrict__ bout,
    float* __restrict__ sbuf)
{
    __shared__ float xs[EBLK * 65];    // 33.3 KB activations
    __shared__ float scat[16 * 68];    // 4.35 KB transpose batch
    __shared__ int   segLDS[EBLK];
    __shared__ int   segedge[2];
    const int tid  = threadIdx.x;
    const int lane = tid & 63;
    const int s0   = blockIdx.x * EBLK;
    const int slot = s0 + tid;

    const int seg = slotseg[slot];
    const int g   = (seg >= 0) ? elist[slot] : 0;
    int first = 0, second = 0;
    if (seg >= 0) {
        if (g < E) { first = ni[g];     second = bi[g];     }
        else       { first = bi[g - E]; second = ni[g - E]; }
    }
    segLDS[tid] = seg;
    if (tid == 0) segedge[0] = slotseg[s0 - 1];
    if (tid == 1) segedge[1] = slotseg[s0 + EBLK];

    // ---- stage 1: x = gelu(ptop[first] + pbot[second]) -> xs ----
    {
        const float4* pa = (const float4*)(p + (size_t)first  * DDIM);        // top
        const float4* pb = (const float4*)(p + (size_t)second * DDIM + 64);   // bot
        #pragma unroll 4
        for (int q = 0; q < 16; ++q) {
            float4 a = pa[q], b = pb[q];
            xs[tid * 65 + q * 4 + 0] = gelu_exact(a.x + b.x);
            xs[tid * 65 + q * 4 + 1] = gelu_exact(a.y + b.y);
            xs[tid * 65 + q * 4 + 2] = gelu_exact(a.z + b.z);
            xs[tid * 65 + q * 4 + 3] = gelu_exact(a.w + b.w);
        }
    }

    // ---- 3 hidden layers 64x64, weights direct from global ----
    for (int L = 0; L < 3; ++L) {
        float acc[64];
        #pragma unroll
        for (int j = 0; j < 64; ++j) acc[j] = bhid[L * 64 + j];
        #pragma unroll 4
        for (int k = 0; k < 64; ++k) {
            const float xk = xs[tid * 65 + k];
            const float* wr = Whid + (size_t)L * 4096 + (size_t)k * 64;
            #pragma unroll
            for (int j = 0; j < 64; ++j) acc[j] = fmaf(xk, wr[j], acc[j]);
        }
        #pragma unroll
        for (int j = 0; j < 64; ++j) xs[tid * 65 + j] = gelu_exact(acc[j]);
    }

    // ---- output 64x128 (two halves) + fused segmented reduction ----
    for (int half = 0; half < 2; ++half) {
        float acc[64];
        #pragma unroll
        for (int j = 0; j < 64; ++j) acc[j] = bout[half * 64 + j];
        #pragma unroll 4
        for (int k = 0; k < 64; ++k) {
            const float xk = xs[tid * 65 + k];
            const float* wr = Wout + (size_t)k * 128 + half * 64;
            #pragma unroll
            for (int j = 0; j < 64; ++j) acc[j] = fmaf(xk, wr[j], acc[j]);
        }

        int   runSeg = -2;
        float runacc = 0.0f;
        bool  leftC  = true;
        for (int b = 0; b < 8; ++b) {
            __syncthreads();
            if ((tid >> 4) == b) {
                float4* dp = (float4*)&scat[(tid & 15) * 68];
                #pragma unroll
                for (int q = 0; q < 16; ++q)
                    dp[q] = make_float4(acc[q*4], acc[q*4+1], acc[q*4+2], acc[q*4+3]);
            }
            __syncthreads();
            if (tid < 64) {
                for (int r = 0; r < 16; ++r) {
                    const int rowi = b * 16 + r;
                    const int sg = segLDS[rowi];
                    const float v = scat[r * 68 + lane];
                    if (sg != runSeg) {
                        if (runSeg >= 0) {
                            float* pp = sbuf + (size_t)runSeg * DDIM + half * 64 + lane;
                            if (leftC) *pp = runacc;
                            else       atomicAdd(pp, runacc);
                        }
                        runSeg = sg;
                        runacc = v;
                        leftC  = (rowi == 0) ? (segedge[0] != sg) : true;
                    } else {
                        runacc += v;
                    }
                }
            }
        }
        if (tid < 64 && runSeg >= 0) {
            const bool rightC = (segedge[1] != runSeg);
            float* pp = sbuf + (size_t)runSeg * DDIM + half * 64 + lane;
            if (leftC && rightC) *pp = runacc;
            else                 atomicAdd(pp, runacc);
        }
        __syncthreads();
    }
}

// Chunked GRU, weights direct from global (uniform/scalar). No LDS at all.
// Writes h' to a third buffer (hout != h != msum).
__global__ __launch_bounds__(256) void gru_kernel3(
    const float* __restrict__ h, const float* __restrict__ msum,
    const int* __restrict__ deg,
    const float* __restrict__ Wx, const float* __restrict__ Wh,
    const float* __restrict__ bi, const float* __restrict__ br,
    float* __restrict__ hout)
{
    const int node = blockIdx.x * 256 + threadIdx.x;
    const int dg   = deg[node];
    const float cinv = (dg > 0) ? (1.0f / (float)dg) : 0.0f;
    const float4* m4p = (const float4*)(msum + (size_t)node * DDIM);
    const float4* h4p = (const float4*)(h    + (size_t)node * DDIM);
    float* orow = hout + (size_t)node * DDIM;

    for (int ch = 0; ch < 8; ++ch) {
        const int j0 = ch * 16;
        float az[16], ar[16], ax[16], ah[16];
        #pragma unroll
        for (int j = 0; j < 16; ++j) {
            az[j] = bi[j0 + j]       + br[j0 + j];
            ar[j] = bi[128 + j0 + j] + br[128 + j0 + j];
            ax[j] = bi[256 + j0 + j];
            ah[j] = br[256 + j0 + j];
        }
        for (int k4 = 0; k4 < 32; ++k4) {
            float4 mv4 = m4p[k4];
            float4 hv4 = h4p[k4];
            #pragma unroll
            for (int kk = 0; kk < 4; ++kk) {
                const int k = k4 * 4 + kk;
                const float mk = (&mv4.x)[kk] * cinv;
                const float hk = (&hv4.x)[kk];
                const float* wx = Wx + (size_t)k * 384 + j0;
                const float* wh = Wh + (size_t)k * 384 + j0;
                #pragma unroll
                for (int j = 0; j < 16; ++j) {
                    az[j] = fmaf(mk, wx[j],       az[j]);
                    az[j] = fmaf(hk, wh[j],       az[j]);
                    ar[j] = fmaf(mk, wx[128 + j], ar[j]);
                    ar[j] = fmaf(hk, wh[128 + j], ar[j]);
                    ax[j] = fmaf(mk, wx[256 + j], ax[j]);
                    ah[j] = fmaf(hk, wh[256 + j], ah[j]);
                }
            }
        }
        float4 hj4[4];
        #pragma unroll
        for (int q = 0; q < 4; ++q) hj4[q] = h4p[ch * 4 + q];
        float4 o[4];
        #pragma unroll
        for (int j = 0; j < 16; ++j) {
            float z    = sigmoidf_(az[j]);
            float r    = sigmoidf_(ar[j]);
            float cand = tanhf(ax[j] + r * ah[j]);
            float hv   = (&hj4[j >> 2].x)[j & 3];
            (&o[j >> 2].x)[j & 3] = z * hv + (1.0f - z) * cand;
        }
        #pragma unroll
        for (int q = 0; q < 4; ++q) ((float4*)orow)[ch * 4 + q] = o[q];
    }
}

// Readout: block=64, activations in LDS slice, weights direct from global.
__global__ __launch_bounds__(64) void readout_kernel(
    const float* __restrict__ h,
    const float* __restrict__ Win,  const float* __restrict__ bin,
    const float* __restrict__ Whid, const float* __restrict__ bhid,
    const float* __restrict__ Wout, const float* __restrict__ bout,
    float* __restrict__ out)
{
    __shared__ float xs[64 * 65];   // 16.6 KB
    const int tid = threadIdx.x;
    const int row = blockIdx.x * 64 + tid;        // 0..31999
    const int b = row / 1000, n = row % 1000;
    const float4* xrow = (const float4*)(h + ((size_t)b * 4000 + n) * DDIM);

    {
        float acc[64];
        #pragma unroll
        for (int j = 0; j < 64; ++j) acc[j] = bin[j];
        #pragma unroll 2
        for (int k4 = 0; k4 < 32; ++k4) {
            float4 xv = xrow[k4];
            #pragma unroll
            for (int kk = 0; kk < 4; ++kk) {
                const float xk = (&xv.x)[kk];
                const float* wr = Win + (size_t)(k4 * 4 + kk) * 64;
                #pragma unroll
                for (int j = 0; j < 64; ++j) acc[j] = fmaf(xk, wr[j], acc[j]);
            }
        }
        #pragma unroll
        for (int j = 0; j < 64; ++j) xs[tid * 65 + j] = gelu_exact(acc[j]);
    }

    for (int L = 0; L < 3; ++L) {
        float acc[64];
        #pragma unroll
        for (int j = 0; j < 64; ++j) acc[j] = bhid[L * 64 + j];
        #pragma unroll 4
        for (int k = 0; k < 64; ++k) {
            const float xk = xs[tid * 65 + k];
            const float* wr = Whid + (size_t)L * 4096 + (size_t)k * 64;
            #pragma unroll
            for (int j = 0; j < 64; ++j) acc[j] = fmaf(xk, wr[j], acc[j]);
        }
        #pragma unroll
        for (int j = 0; j < 64; ++j) xs[tid * 65 + j] = gelu_exact(acc[j]);
    }

    float acc[10];
    #pragma unroll
    for (int pj = 0; pj < 10; ++pj) acc[pj] = bout[pj];
    #pragma unroll 4
    for (int k = 0; k < 64; ++k) {
        const float xk = xs[tid * 65 + k];
        const float* wr = Wout + k * 10;
        #pragma unroll
        for (int pj = 0; pj < 10; ++pj) acc[pj] = fmaf(xk, wr[pj], acc[pj]);
    }
    #pragma unroll
    for (int pj = 0; pj < 10; ++pj) out[(size_t)row * 10 + pj] = acc[pj];
}

extern "C" void kernel_launch(void* const* d_in, const int* in_sizes, int n_in,
                              void* d_out, int out_size, void* d_ws, size_t ws_size,
                              hipStream_t stream) {
    const int*   node_inputs = (const int*)d_in[0];
    const int*   ni_int = (const int*)d_in[1];
    const int*   bi_int = (const int*)d_in[2];
    const int*   ni_tmp = (const int*)d_in[3];
    const int*   bi_tmp = (const int*)d_in[4];
    const float* embed  = (const float*)d_in[5];
    const float* mWin   = (const float*)d_in[6];
    const float* mbin   = (const float*)d_in[7];
    const float* mWhid  = (const float*)d_in[8];
    const float* mbhid  = (const float*)d_in[9];
    const float* mWout  = (const float*)d_in[10];
    const float* mbout  = (const float*)d_in[11];
    const float* roWin  = (const float*)d_in[12];
    const float* robin  = (const float*)d_in[13];
    const float* roWhid = (const float*)d_in[14];
    const float* robhid = (const float*)d_in[15];
    const float* roWout = (const float*)d_in[16];
    const float* robout = (const float*)d_in[17];
    const float* giWx = (const float*)d_in[18];
    const float* giWh = (const float*)d_in[19];
    const float* gibi = (const float*)d_in[20];
    const float* gibr = (const float*)d_in[21];
    const float* gtWx = (const float*)d_in[22];
    const float* gtWh = (const float*)d_in[23];
    const float* gtbi = (const float*)d_in[24];
    const float* gtbr = (const float*)d_in[25];
    float* out = (float*)d_out;

    const int E_INT = 200000, E_TMP = 96000;
    const int NSLOT_I = 400000;   // 3125*128 exact
    const int NSLOT_T = 192000;   // 1500*128 exact

    char* ws = (char*)d_ws;
    float* A  = (float*)(ws);                 // h
    float* Bs = (float*)(ws + HBYTES);        // segment sums
    float* C  = (float*)(ws + 2 * HBYTES);    // scratch: p, then h'
    char*  ib = ws + 3 * HBYTES;

    int* deg_i   = (int*)(ib);
    int* deg_t   = (int*)(ib + 512000);
    int* offp_i  = (int*)(ib + 1024000);
    int* offp_t  = (int*)(ib + 1536000);
    int* bexc_i  = (int*)(ib + 2048000);
    int* bexc_t  = (int*)(ib + 2052096);
    int* bsum    = (int*)(ib + 2056192);
    int* cursor  = (int*)(ib + 2060288);
    int* el_i    = (int*)(ib + 2572288);            // 400000*4
    int* el_t    = (int*)(ib + 4172288);            // 192000*4
    int* ssi_raw = (int*)(ib + 4940288);            // (1+400000+1)*4
    int* sst_raw = (int*)(ib + 6540296);            // (1+192000+1)*4
    int* ssi = ssi_raw + 1;
    int* sst = sst_raw + 1;

    embed_kernel<<<16000, 256, 0, stream>>>(node_inputs, embed, A);

    hipMemsetAsync(deg_i, 0, NTOT * sizeof(int), stream);
    hipMemsetAsync(deg_t, 0, NTOT * sizeof(int), stream);
    hist_kernel<<<(2 * E_INT + 255) / 256, 256, 0, stream>>>(ni_int, bi_int, E_INT, deg_i);
    hist_kernel<<<(2 * E_TMP + 255) / 256, 256, 0, stream>>>(ni_tmp, bi_tmp, E_TMP, deg_t);

    hipMemsetAsync(ssi_raw, 0xFF, (size_t)(NSLOT_I + 2) * sizeof(int), stream);
    hipMemsetAsync(sst_raw, 0xFF, (size_t)(NSLOT_T + 2) * sizeof(int), stream);

    blockscan_kernel<<<500, 256, 0, stream>>>(deg_i, offp_i, bsum);
    bscan_kernel<<<1, 512, 0, stream>>>(bsum, bexc_i, 500);
    hipMemsetAsync(cursor, 0, NTOT * sizeof(int), stream);
    fill_kernel<<<(2 * E_INT + 255) / 256, 256, 0, stream>>>(
        ni_int, bi_int, E_INT, offp_i, bexc_i, cursor, el_i, ssi);

    blockscan_kernel<<<500, 256, 0, stream>>>(deg_t, offp_t, bsum);
    bscan_kernel<<<1, 512, 0, stream>>>(bsum, bexc_t, 500);
    hipMemsetAsync(cursor, 0, NTOT * sizeof(int), stream);
    fill_kernel<<<(2 * E_TMP + 255) / 256, 256, 0, stream>>>(
        ni_tmp, bi_tmp, E_TMP, offp_t, bexc_t, cursor, el_t, sst);

    // rotation: (A=h, Bs=sum, C=scratch) -> after phase: (C, A, Bs)
    for (int ph = 0; ph < 4; ++ph) {
        const bool isInt = (ph % 2 == 0);
        node_pre_kernel<<<NTOT / 256, 256, 0, stream>>>(A, mWin, mbin, C);
        hipMemsetAsync(Bs, 0, HBYTES, stream);
        if (isInt) {
            edge_mlp_kernel3<<<NSLOT_I / EBLK, EBLK, 0, stream>>>(
                ni_int, bi_int, E_INT, el_i, ssi, C,
                mWhid, mbhid, mWout, mbout, Bs);
            gru_kernel3<<<NTOT / 256, 256, 0, stream>>>(
                A, Bs, deg_i, giWx, giWh, gibi, gibr, C);
        } else {
            edge_mlp_kernel3<<<NSLOT_T / EBLK, EBLK, 0, stream>>>(
                ni_tmp, bi_tmp, E_TMP, el_t, sst, C,
                mWhid, mbhid, mWout, mbout, Bs);
            gru_kernel3<<<NTOT / 256, 256, 0, stream>>>(
                A, Bs, deg_t, gtWx, gtWh, gtbi, gtbr, C);
        }
        float* oldA = A;  A = C;  C = Bs;  Bs = oldA;
    }

    readout_kernel<<<500, 64, 0, stream>>>(
        A, roWin, robin, roWhid, robhid, roWout, robout, out);
}